// Round 2
// baseline (1149.288 us; speedup 1.0000x reference)
//
#include <hip/hip_runtime.h>

#define N_NODES 50000
#define E_EDGES 800000
#define CIN     32
#define COUT    64

// One wave (64 lanes) per edge; lane = output channel.
// row/col/pseudo/basis/wi are wave-uniform -> scalarized loads for x row.
// Weight loads W[k][i][lane] are coalesced 256B per instruction.
__global__ __launch_bounds__(256) void edge_kernel(
    const float* __restrict__ x,
    const int* __restrict__ ei,          // int32 per harness contract
    const float* __restrict__ pseudo,
    const float* __restrict__ weight,
    float* __restrict__ out,
    float* __restrict__ deg)
{
    const int wave   = (blockIdx.x * blockDim.x + threadIdx.x) >> 6;
    const int lane   = threadIdx.x & 63;
    const int nwaves = (gridDim.x * blockDim.x) >> 6;

    for (int e = wave; e < E_EDGES; e += nwaves) {
        int row = ei[e];
        int col = ei[E_EDGES + e];
        // defensive clamp: an indexing bug becomes a numeric error, not a fault
        row = min(max(row, 0), N_NODES - 1);
        col = min(max(col, 0), N_NODES - 1);

        const float p0 = pseudo[2 * e];
        const float p1 = pseudo[2 * e + 1];

        // spline basis, DEGREE=1, KS=5: v = p*(KS-1)
        const float v0 = p0 * 4.0f;
        const float v1 = p1 * 4.0f;
        const float fl0 = floorf(v0);
        const float fl1 = floorf(v1);
        const float f0 = v0 - fl0;
        const float f1 = v1 - fl1;
        const int lo0 = min(max((int)fl0, 0), 3);
        const int lo1 = min(max((int)fl1, 0), 3);

        // s indexed by bits (dim0 = bit0, dim1 = bit1); offsets = (1, 5)
        const float b0 = (1.0f - f0) * (1.0f - f1); // wi = base
        const float b1 = f0 * (1.0f - f1);          // wi = base + 1
        const float b2 = (1.0f - f0) * f1;          // wi = base + 5
        const float b3 = f0 * f1;                   // wi = base + 6
        const int base = lo0 + 5 * lo1;

        const float* __restrict__ w0 = weight + (size_t)(base)     * (CIN * COUT) + lane;
        const float* __restrict__ w1 = weight + (size_t)(base + 1) * (CIN * COUT) + lane;
        const float* __restrict__ w2 = weight + (size_t)(base + 5) * (CIN * COUT) + lane;
        const float* __restrict__ w3 = weight + (size_t)(base + 6) * (CIN * COUT) + lane;
        const float* __restrict__ xp = x + (size_t)col * CIN;

        float d0 = 0.0f, d1 = 0.0f, d2 = 0.0f, d3 = 0.0f;
#pragma unroll
        for (int i = 0; i < CIN; ++i) {
            const float xv = xp[i];  // wave-uniform -> s_load
            d0 += xv * w0[i * COUT];
            d1 += xv * w1[i * COUT];
            d2 += xv * w2[i * COUT];
            d3 += xv * w3[i * COUT];
        }
        const float acc = b0 * d0 + b1 * d1 + b2 * d2 + b3 * d3;

        atomicAdd(&out[(size_t)row * COUT + lane], acc);
        if (lane == 0) atomicAdd(&deg[row], 1.0f);
    }
}

// out = out / max(deg,1) + x @ root + bias
__global__ __launch_bounds__(256) void final_kernel(
    const float* __restrict__ x,
    const float* __restrict__ root,
    const float* __restrict__ bias,
    const float* __restrict__ deg,
    float* __restrict__ out)
{
    const int wave   = (blockIdx.x * blockDim.x + threadIdx.x) >> 6;
    const int lane   = threadIdx.x & 63;
    const int nwaves = (gridDim.x * blockDim.x) >> 6;

    for (int n = wave; n < N_NODES; n += nwaves) {
        const float* __restrict__ xp = x + (size_t)n * CIN;
        float acc = bias[lane];
#pragma unroll
        for (int i = 0; i < CIN; ++i)
            acc += xp[i] * root[i * COUT + lane];
        float dg = deg[n];
        dg = dg > 1.0f ? dg : 1.0f;
        const size_t idx = (size_t)n * COUT + lane;
        out[idx] = out[idx] / dg + acc;
    }
}

extern "C" void kernel_launch(void* const* d_in, const int* in_sizes, int n_in,
                              void* d_out, int out_size, void* d_ws, size_t ws_size,
                              hipStream_t stream) {
    const float* x      = (const float*)d_in[0];
    const int*   ei     = (const int*)d_in[1];
    const float* pseudo = (const float*)d_in[2];
    const float* weight = (const float*)d_in[3];
    const float* root   = (const float*)d_in[4];
    const float* bias   = (const float*)d_in[5];
    float* out = (float*)d_out;
    float* deg = (float*)d_ws;

    hipMemsetAsync(out, 0, sizeof(float) * (size_t)N_NODES * COUT, stream);
    hipMemsetAsync(deg, 0, sizeof(float) * (size_t)N_NODES, stream);

    edge_kernel<<<4096, 256, 0, stream>>>(x, ei, pseudo, weight, out, deg);
    final_kernel<<<1024, 256, 0, stream>>>(x, root, bias, deg, out);
}

// Round 3
// 625.177 us; speedup vs baseline: 1.8383x; 1.8383x over previous
//
#include <hip/hip_runtime.h>

#define N_NODES 50000
#define E_EDGES 800000
#define CIN     32
#define COUT    64
#define NBUCKET 16   // (lo0, lo1) in [0,3]^2

// ---------- pass 1: per-edge cell histogram + degree count ----------
__global__ __launch_bounds__(256) void count_kernel(
    const int* __restrict__ ei,
    const float* __restrict__ pseudo,
    int* __restrict__ hist,
    float* __restrict__ deg)
{
    __shared__ int lh[NBUCKET];
    if (threadIdx.x < NBUCKET) lh[threadIdx.x] = 0;
    __syncthreads();

    const int e = blockIdx.x * 256 + threadIdx.x;
    if (e < E_EDGES) {
        int row = ei[e];
        row = min(max(row, 0), N_NODES - 1);
        const float v0 = pseudo[2 * e]     * 4.0f;
        const float v1 = pseudo[2 * e + 1] * 4.0f;
        const int lo0 = min(max((int)floorf(v0), 0), 3);
        const int lo1 = min(max((int)floorf(v1), 0), 3);
        const int cell = lo0 + 4 * lo1;
        atomicAdd(&lh[cell], 1);
        atomicAdd(&deg[row], 1.0f);
    }
    __syncthreads();
    if (threadIdx.x < NBUCKET) atomicAdd(&hist[threadIdx.x], lh[threadIdx.x]);
}

// ---------- pass 2: exclusive scan of 16 bins ----------
__global__ void scan_kernel(const int* __restrict__ hist,
                            int* __restrict__ bstart,
                            int* __restrict__ cursor)
{
    if (threadIdx.x == 0 && blockIdx.x == 0) {
        int acc = 0;
        for (int c = 0; c < NBUCKET; ++c) {
            bstart[c] = acc;
            cursor[c] = acc;
            acc += hist[c];
        }
    }
}

// ---------- pass 3: scatter edge ids into bucket lists ----------
__global__ __launch_bounds__(256) void scatter_kernel(
    const float* __restrict__ pseudo,
    int* __restrict__ cursor,
    int* __restrict__ list)
{
    __shared__ int lh[NBUCKET];
    __shared__ int lbase[NBUCKET];
    if (threadIdx.x < NBUCKET) lh[threadIdx.x] = 0;
    __syncthreads();

    const int e = blockIdx.x * 256 + threadIdx.x;
    int cell = 0, myoff = 0;
    if (e < E_EDGES) {
        const float v0 = pseudo[2 * e]     * 4.0f;
        const float v1 = pseudo[2 * e + 1] * 4.0f;
        const int lo0 = min(max((int)floorf(v0), 0), 3);
        const int lo1 = min(max((int)floorf(v1), 0), 3);
        cell = lo0 + 4 * lo1;
        myoff = atomicAdd(&lh[cell], 1);
    }
    __syncthreads();
    if (threadIdx.x < NBUCKET)
        lbase[threadIdx.x] = atomicAdd(&cursor[threadIdx.x], lh[threadIdx.x]);
    __syncthreads();
    if (e < E_EDGES)
        list[lbase[cell] + myoff] = e;
}

// ---------- pass 4: per-bucket edge compute, weights in VGPRs ----------
// One wave per edge iteration; lane = output channel. Each wave preloads its
// bucket's 4 weight matrices' lane-column (4 s * 32 i = 128 VGPRs) once,
// then streams edges: 128 v_fmac_f32 per edge with scalar x broadcast.
__global__ __launch_bounds__(256) void bucket_kernel(
    const float* __restrict__ x,
    const int* __restrict__ ei,
    const float* __restrict__ pseudo,
    const float* __restrict__ weight,
    const int* __restrict__ list,
    const int* __restrict__ bstart,
    const int* __restrict__ hist,
    float* __restrict__ out)
{
    const int beta  = blockIdx.x & (NBUCKET - 1);
    const int lane  = threadIdx.x & 63;
    const int waveIdx = (blockIdx.x >> 4) * 4 + (threadIdx.x >> 6);
    const int nWaves  = (gridDim.x >> 4) * 4;

    const int lo0 = beta & 3;
    const int lo1 = beta >> 2;
    const int base = lo0 + 5 * lo1;          // weight index of s=0 corner

    // preload lane's weight columns for the 4 support cells
    float w0[CIN], w1[CIN], w2[CIN], w3[CIN];
    {
        const float* p0 = weight + (size_t)(base)     * (CIN * COUT) + lane;
        const float* p1 = weight + (size_t)(base + 1) * (CIN * COUT) + lane;
        const float* p2 = weight + (size_t)(base + 5) * (CIN * COUT) + lane;
        const float* p3 = weight + (size_t)(base + 6) * (CIN * COUT) + lane;
#pragma unroll
        for (int i = 0; i < CIN; ++i) {
            w0[i] = p0[i * COUT];
            w1[i] = p1[i * COUT];
            w2[i] = p2[i * COUT];
            w3[i] = p3[i * COUT];
        }
    }

    const int start = bstart[beta];
    const int cnt   = hist[beta];

    for (int idx = waveIdx; idx < cnt; idx += nWaves) {
        const int e = __builtin_amdgcn_readfirstlane(list[start + idx]);
        int row = __builtin_amdgcn_readfirstlane(ei[e]);
        int col = __builtin_amdgcn_readfirstlane(ei[E_EDGES + e]);
        row = min(max(row, 0), N_NODES - 1);
        col = min(max(col, 0), N_NODES - 1);

        const float v0 = pseudo[2 * e]     * 4.0f;
        const float v1 = pseudo[2 * e + 1] * 4.0f;
        const float f0 = v0 - floorf(v0);
        const float f1 = v1 - floorf(v1);
        const float b0 = (1.0f - f0) * (1.0f - f1);
        const float b1 = f0 * (1.0f - f1);
        const float b2 = (1.0f - f0) * f1;
        const float b3 = f0 * f1;

        const float* __restrict__ xp = x + (size_t)col * CIN;  // uniform -> s_load
        float d0 = 0.0f, d1 = 0.0f, d2 = 0.0f, d3 = 0.0f;
#pragma unroll
        for (int i = 0; i < CIN; ++i) {
            const float xv = xp[i];
            d0 += xv * w0[i];
            d1 += xv * w1[i];
            d2 += xv * w2[i];
            d3 += xv * w3[i];
        }
        const float acc = b0 * d0 + b1 * d1 + b2 * d2 + b3 * d3;
        atomicAdd(&out[(size_t)row * COUT + lane], acc);
    }
}

// ---------- finalize: out = out/max(deg,1) + x@root + bias ----------
__global__ __launch_bounds__(256) void final_kernel(
    const float* __restrict__ x,
    const float* __restrict__ root,
    const float* __restrict__ bias,
    const float* __restrict__ deg,
    float* __restrict__ out)
{
    const int wave   = (blockIdx.x * blockDim.x + threadIdx.x) >> 6;
    const int lane   = threadIdx.x & 63;
    const int nwaves = (gridDim.x * blockDim.x) >> 6;

    for (int n = wave; n < N_NODES; n += nwaves) {
        const float* __restrict__ xp = x + (size_t)n * CIN;
        float acc = bias[lane];
#pragma unroll
        for (int i = 0; i < CIN; ++i)
            acc += xp[i] * root[i * COUT + lane];
        float dg = deg[n];
        dg = dg > 1.0f ? dg : 1.0f;
        const size_t idx = (size_t)n * COUT + lane;
        out[idx] = out[idx] / dg + acc;
    }
}

extern "C" void kernel_launch(void* const* d_in, const int* in_sizes, int n_in,
                              void* d_out, int out_size, void* d_ws, size_t ws_size,
                              hipStream_t stream) {
    const float* x      = (const float*)d_in[0];
    const int*   ei     = (const int*)d_in[1];
    const float* pseudo = (const float*)d_in[2];
    const float* weight = (const float*)d_in[3];
    const float* root   = (const float*)d_in[4];
    const float* bias   = (const float*)d_in[5];
    float* out = (float*)d_out;

    char* w = (char*)d_ws;
    float* deg   = (float*)w;                    // 50000 floats = 200000 B
    int*   hist  = (int*)(w + 200064);           // 16 ints
    int*   bstart= (int*)(w + 200128);           // 16 ints
    int*   cursor= (int*)(w + 200192);           // 16 ints
    int*   list  = (int*)(w + 200256);           // 800000 ints = 3.2 MB

    hipMemsetAsync(out, 0, sizeof(float) * (size_t)N_NODES * COUT, stream);
    hipMemsetAsync(deg, 0, sizeof(float) * (size_t)N_NODES, stream);
    hipMemsetAsync(hist, 0, 192, stream);        // hist+bstart+cursor

    const int eblocks = (E_EDGES + 255) / 256;   // 3125
    count_kernel  <<<eblocks, 256, 0, stream>>>(ei, pseudo, hist, deg);
    scan_kernel   <<<1, 64, 0, stream>>>(hist, bstart, cursor);
    scatter_kernel<<<eblocks, 256, 0, stream>>>(pseudo, cursor, list);
    bucket_kernel <<<16 * 64, 256, 0, stream>>>(x, ei, pseudo, weight,
                                                list, bstart, hist, out);
    final_kernel  <<<1024, 256, 0, stream>>>(x, root, bias, deg, out);
}

// Round 4
// 373.137 us; speedup vs baseline: 3.0801x; 1.6755x over previous
//
#include <hip/hip_runtime.h>
#include <hip/hip_bf16.h>

#define N_NODES 50000
#define E_EDGES 800000
#define CIN     32
#define COUT    64
#define NBUCKET 16   // (lo0, lo1) in [0,3]^2
#define KPAD    136  // 128 bf16 + 8 pad (breaks 256B-stride bank conflict)

typedef __attribute__((ext_vector_type(8))) short s8v;   // 8 bf16 = 4 VGPRs
typedef __attribute__((ext_vector_type(4))) float f4v;

static __device__ inline unsigned short f2bf(float f) {  // RTNE fp32->bf16
    unsigned u = __builtin_bit_cast(unsigned, f);
    u += 0x7fff + ((u >> 16) & 1);
    return (unsigned short)(u >> 16);
}

// ---------- pass 1: per-edge cell histogram + degree count ----------
__global__ __launch_bounds__(256) void count_kernel(
    const int* __restrict__ ei,
    const float* __restrict__ pseudo,
    int* __restrict__ hist,
    float* __restrict__ deg)
{
    __shared__ int lh[NBUCKET];
    if (threadIdx.x < NBUCKET) lh[threadIdx.x] = 0;
    __syncthreads();

    const int e = blockIdx.x * 256 + threadIdx.x;
    if (e < E_EDGES) {
        int row = ei[e];
        row = min(max(row, 0), N_NODES - 1);
        const float v0 = pseudo[2 * e]     * 4.0f;
        const float v1 = pseudo[2 * e + 1] * 4.0f;
        const int lo0 = min(max((int)floorf(v0), 0), 3);
        const int lo1 = min(max((int)floorf(v1), 0), 3);
        atomicAdd(&lh[lo0 + 4 * lo1], 1);
        atomicAdd(&deg[row], 1.0f);
    }
    __syncthreads();
    if (threadIdx.x < NBUCKET) atomicAdd(&hist[threadIdx.x], lh[threadIdx.x]);
}

// ---------- pass 2: exclusive scan of 16 bins ----------
__global__ void scan_kernel(const int* __restrict__ hist,
                            int* __restrict__ bstart,
                            int* __restrict__ cursor)
{
    if (threadIdx.x == 0 && blockIdx.x == 0) {
        int acc = 0;
        for (int c = 0; c < NBUCKET; ++c) {
            bstart[c] = acc;
            cursor[c] = acc;
            acc += hist[c];
        }
    }
}

// ---------- pass 3: scatter edge ids into bucket lists ----------
__global__ __launch_bounds__(256) void scatter_kernel(
    const float* __restrict__ pseudo,
    int* __restrict__ cursor,
    int* __restrict__ list)
{
    __shared__ int lh[NBUCKET];
    __shared__ int lbase[NBUCKET];
    if (threadIdx.x < NBUCKET) lh[threadIdx.x] = 0;
    __syncthreads();

    const int e = blockIdx.x * 256 + threadIdx.x;
    int cell = 0, myoff = 0;
    if (e < E_EDGES) {
        const float v0 = pseudo[2 * e]     * 4.0f;
        const float v1 = pseudo[2 * e + 1] * 4.0f;
        const int lo0 = min(max((int)floorf(v0), 0), 3);
        const int lo1 = min(max((int)floorf(v1), 0), 3);
        cell = lo0 + 4 * lo1;
        myoff = atomicAdd(&lh[cell], 1);
    }
    __syncthreads();
    if (threadIdx.x < NBUCKET)
        lbase[threadIdx.x] = atomicAdd(&cursor[threadIdx.x], lh[threadIdx.x]);
    __syncthreads();
    if (e < E_EDGES)
        list[lbase[cell] + myoff] = e;
}

// ---------- pass 4: per-bucket MFMA edge compute ----------
// One wave per 16-edge tile. X'[e][k=s*32+i] = b_s(e) * x[col(e)][i] staged
// bf16 in LDS (per-wave region); Wstack B-fragments live in 64 VGPRs.
// msg tile = X'(16x128) @ Wstack(128x64) via 16x mfma_f32_16x16x32_bf16.
__global__ __launch_bounds__(256, 2) void bucket_mfma_kernel(
    const float* __restrict__ x,
    const int* __restrict__ ei,
    const float* __restrict__ pseudo,
    const float* __restrict__ weight,
    const int* __restrict__ list,
    const int* __restrict__ bstart,
    const int* __restrict__ hist,
    float* __restrict__ out)
{
    __shared__ short XS[4][16 * KPAD];   // 17408 B, wave-private slices

    const int lane = threadIdx.x & 63;
    const int wid  = threadIdx.x >> 6;
    const int beta = blockIdx.x & (NBUCKET - 1);
    const int wGlob   = (blockIdx.x >> 4) * 4 + wid;
    const int wStride = (gridDim.x >> 4) * 4;

    const int lo0 = beta & 3, lo1 = beta >> 2;
    const int base = lo0 + 5 * lo1;            // weight idx of s=0 corner
    const int offs[4] = {0, 1, 5, 6};

    const int q = lane >> 4;     // quad
    const int c = lane & 15;     // col within 16

    // B-fragments: bfr[s][nt] holds Wstack[k=s*32+q*8+j][o=nt*16+c], j=0..7
    s8v bfr[4][4];
#pragma unroll
    for (int s = 0; s < 4; ++s) {
        const float* wp = weight + (size_t)(base + offs[s]) * (CIN * COUT);
#pragma unroll
        for (int nt = 0; nt < 4; ++nt) {
            union { unsigned short u[8]; s8v v; } tmp;
#pragma unroll
            for (int j = 0; j < 8; ++j)
                tmp.u[j] = f2bf(wp[(q * 8 + j) * COUT + nt * 16 + c]);
            bfr[s][nt] = tmp.v;
        }
    }

    const int start  = bstart[beta];
    const int cnt    = hist[beta];
    const int ntiles = (cnt + 15) >> 4;

    for (int t = wGlob; t < ntiles; t += wStride) {
        const int ebase = start + t * 16;

        // metadata: lanes 0..15 own one edge each; padded edges get b=0
        int rowv = 0, colv = 0;
        float b0 = 0.f, b1 = 0.f, b2 = 0.f, b3 = 0.f;
        if (lane < 16 && (t * 16 + lane) < cnt) {
            const int e = list[ebase + lane];
            rowv = min(max(ei[e], 0), N_NODES - 1);
            colv = min(max(ei[E_EDGES + e], 0), N_NODES - 1);
            const float v0 = pseudo[2 * e]     * 4.0f;
            const float v1 = pseudo[2 * e + 1] * 4.0f;
            const float f0 = v0 - floorf(v0);
            const float f1 = v1 - floorf(v1);
            b0 = (1.0f - f0) * (1.0f - f1);
            b1 = f0 * (1.0f - f1);
            b2 = (1.0f - f0) * f1;
            b3 = f0 * f1;
        }

        // gather + scale + stage: lane -> edge=lane>>2, part=lane&3 (8 floats)
        {
            const int eg = lane >> 2, part = lane & 3;
            const int  gc = __shfl(colv, eg);
            const float ss0 = __shfl(b0, eg), ss1 = __shfl(b1, eg);
            const float ss2 = __shfl(b2, eg), ss3 = __shfl(b3, eg);
            const float ss[4] = {ss0, ss1, ss2, ss3};
            const float* xp = x + (size_t)gc * CIN + part * 8;
            float xv[8];
            *(f4v*)&xv[0] = *(const f4v*)xp;
            *(f4v*)&xv[4] = *(const f4v*)(xp + 4);
            short* dst = &XS[wid][eg * KPAD + part * 8];
#pragma unroll
            for (int s = 0; s < 4; ++s) {
                union { unsigned short u[8]; s8v v; } tmp;
#pragma unroll
                for (int j = 0; j < 8; ++j)
                    tmp.u[j] = f2bf(ss[s] * xv[j]);
                *(s8v*)(dst + s * 32) = tmp.v;     // 16B ds_write_b128
            }
        }
        __builtin_amdgcn_wave_barrier();   // wave-sync LDS RAW (in-order DS)

        // A-fragments: A[m=c][k=ks*32 + q*8 + j]
        s8v afr[4];
        {
            const short* ap = &XS[wid][c * KPAD + q * 8];
#pragma unroll
            for (int ks = 0; ks < 4; ++ks)
                afr[ks] = *(const s8v*)(ap + ks * 32);
        }
        __builtin_amdgcn_wave_barrier();

        // MFMA: acc[nt] (16 edges x 16 outs), K=128 in 4 steps
        f4v acc[4];
#pragma unroll
        for (int nt = 0; nt < 4; ++nt) {
            acc[nt] = (f4v){0.f, 0.f, 0.f, 0.f};
#pragma unroll
            for (int ks = 0; ks < 4; ++ks)
                acc[nt] = __builtin_amdgcn_mfma_f32_16x16x32_bf16(
                    afr[ks], bfr[ks][nt], acc[nt], 0, 0, 0);
        }

        // epilogue: C/D row = q*4+r (edge), col = c (out within tile)
#pragma unroll
        for (int r = 0; r < 4; ++r) {
            const int m = q * 4 + r;
            const int orow = __shfl(rowv, m);   // padded edges add 0.0 to row 0
#pragma unroll
            for (int nt = 0; nt < 4; ++nt)
                atomicAdd(&out[(size_t)orow * COUT + nt * 16 + c], acc[nt][r]);
        }
    }
}

// ---------- finalize: out = out/max(deg,1) + x@root + bias (fp32) ----------
__global__ __launch_bounds__(256) void final_kernel(
    const float* __restrict__ x,
    const float* __restrict__ root,
    const float* __restrict__ bias,
    const float* __restrict__ deg,
    float* __restrict__ out)
{
    const int wave   = (blockIdx.x * blockDim.x + threadIdx.x) >> 6;
    const int lane   = threadIdx.x & 63;
    const int nwaves = (gridDim.x * blockDim.x) >> 6;

    for (int n = wave; n < N_NODES; n += nwaves) {
        const float* __restrict__ xp = x + (size_t)n * CIN;
        float acc = bias[lane];
#pragma unroll
        for (int i = 0; i < CIN; ++i)
            acc += xp[i] * root[i * COUT + lane];
        float dg = deg[n];
        dg = dg > 1.0f ? dg : 1.0f;
        const size_t idx = (size_t)n * COUT + lane;
        out[idx] = out[idx] / dg + acc;
    }
}

extern "C" void kernel_launch(void* const* d_in, const int* in_sizes, int n_in,
                              void* d_out, int out_size, void* d_ws, size_t ws_size,
                              hipStream_t stream) {
    const float* x      = (const float*)d_in[0];
    const int*   ei     = (const int*)d_in[1];
    const float* pseudo = (const float*)d_in[2];
    const float* weight = (const float*)d_in[3];
    const float* root   = (const float*)d_in[4];
    const float* bias   = (const float*)d_in[5];
    float* out = (float*)d_out;

    char* w = (char*)d_ws;
    float* deg   = (float*)w;                    // 50000 floats
    int*   hist  = (int*)(w + 200064);
    int*   bstart= (int*)(w + 200128);
    int*   cursor= (int*)(w + 200192);
    int*   list  = (int*)(w + 200256);           // 800000 ints

    hipMemsetAsync(out, 0, sizeof(float) * (size_t)N_NODES * COUT, stream);
    hipMemsetAsync(deg, 0, sizeof(float) * (size_t)N_NODES, stream);
    hipMemsetAsync(hist, 0, 192, stream);        // hist+bstart+cursor

    const int eblocks = (E_EDGES + 255) / 256;
    count_kernel     <<<eblocks, 256, 0, stream>>>(ei, pseudo, hist, deg);
    scan_kernel      <<<1, 64, 0, stream>>>(hist, bstart, cursor);
    scatter_kernel   <<<eblocks, 256, 0, stream>>>(pseudo, cursor, list);
    bucket_mfma_kernel<<<16 * 64, 256, 0, stream>>>(x, ei, pseudo, weight,
                                                    list, bstart, hist, out);
    final_kernel     <<<1024, 256, 0, stream>>>(x, root, bias, deg, out);
}

// Round 5
// 312.117 us; speedup vs baseline: 3.6822x; 1.1955x over previous
//
#include <hip/hip_runtime.h>

#define N_NODES 50000
#define E_EDGES 800000
#define CIN     32
#define COUT    64
#define NBUCKET 16   // (lo0, lo1) in [0,3]^2
#define KPAD    136  // 128 bf16 + 8 pad

typedef __attribute__((ext_vector_type(8))) short s8v;   // 8 bf16 = 4 VGPRs
typedef __attribute__((ext_vector_type(4))) float f4v;

static __device__ inline unsigned short f2bf(float f) {  // RTNE fp32->bf16
    unsigned u = __builtin_bit_cast(unsigned, f);
    u += 0x7fff + ((u >> 16) & 1);
    return (unsigned short)(u >> 16);
}
static __device__ inline float bf2f(unsigned short h) {
    unsigned u = ((unsigned)h) << 16;
    return __builtin_bit_cast(float, u);
}

// ================= main (CSR) path =================

// pass A: cell histogram + integer degree count
__global__ __launch_bounds__(256) void count_csr(
    const int* __restrict__ ei, const float* __restrict__ pseudo,
    int* __restrict__ hist, int* __restrict__ degi)
{
    __shared__ int lh[NBUCKET];
    if (threadIdx.x < NBUCKET) lh[threadIdx.x] = 0;
    __syncthreads();
    const int e = blockIdx.x * 256 + threadIdx.x;
    if (e < E_EDGES) {
        int row = min(max(ei[e], 0), N_NODES - 1);
        const float v0 = pseudo[2 * e] * 4.0f, v1 = pseudo[2 * e + 1] * 4.0f;
        const int lo0 = min(max((int)floorf(v0), 0), 3);
        const int lo1 = min(max((int)floorf(v1), 0), 3);
        atomicAdd(&lh[lo0 + 4 * lo1], 1);
        atomicAdd(&degi[row], 1);
    }
    __syncthreads();
    if (threadIdx.x < NBUCKET) atomicAdd(&hist[threadIdx.x], lh[threadIdx.x]);
}

// pass B: 16-bucket scan + 50K-node exclusive scan (one workgroup)
__global__ __launch_bounds__(1024) void scan_all(
    const int* __restrict__ hist, int* __restrict__ bstart, int* __restrict__ cursor,
    const int* __restrict__ degi, int* __restrict__ rowstart)
{
    __shared__ int wpart[16];
    __shared__ int carry;
    const int tid = threadIdx.x, lane = tid & 63, wid = tid >> 6;
    if (tid == 0) {
        int acc = 0;
        for (int c = 0; c < NBUCKET; ++c) { bstart[c] = acc; cursor[c] = acc; acc += hist[c]; }
        carry = 0;
    }
    __syncthreads();
    const int nchunk = (N_NODES + 1023) / 1024;
    for (int ch = 0; ch < nchunk; ++ch) {
        const int n = ch * 1024 + tid;
        const int v = (n < N_NODES) ? degi[n] : 0;
        int val = v;
#pragma unroll
        for (int off = 1; off < 64; off <<= 1) {
            int t = __shfl_up(val, off);
            if (lane >= off) val += t;
        }
        if (lane == 63) wpart[wid] = val;
        __syncthreads();
        if (tid == 0) {
            int a = 0;
            for (int w = 0; w < 16; ++w) { int t = wpart[w]; wpart[w] = a; a += t; }
        }
        __syncthreads();
        const int excl = carry + wpart[wid] + (val - v);
        if (n < N_NODES) rowstart[n] = excl;
        __syncthreads();
        if (tid == 1023) carry += wpart[15] + val;
        __syncthreads();
    }
    if (tid == 0) rowstart[N_NODES] = carry;
}

// pass C: scatter edge ids into cell-bucket lists
__global__ __launch_bounds__(256) void scatter_kernel(
    const float* __restrict__ pseudo, int* __restrict__ cursor, int* __restrict__ list)
{
    __shared__ int lh[NBUCKET];
    __shared__ int lbase[NBUCKET];
    if (threadIdx.x < NBUCKET) lh[threadIdx.x] = 0;
    __syncthreads();
    const int e = blockIdx.x * 256 + threadIdx.x;
    int cell = 0, myoff = 0;
    if (e < E_EDGES) {
        const float v0 = pseudo[2 * e] * 4.0f, v1 = pseudo[2 * e + 1] * 4.0f;
        const int lo0 = min(max((int)floorf(v0), 0), 3);
        const int lo1 = min(max((int)floorf(v1), 0), 3);
        cell = lo0 + 4 * lo1;
        myoff = atomicAdd(&lh[cell], 1);
    }
    __syncthreads();
    if (threadIdx.x < NBUCKET)
        lbase[threadIdx.x] = atomicAdd(&cursor[threadIdx.x], lh[threadIdx.x]);
    __syncthreads();
    if (e < E_EDGES)
        list[lbase[cell] + myoff] = e;
}

// pass D: per-bucket MFMA; write per-edge bf16 msg to row-sorted slot (no atomics on out)
__global__ __launch_bounds__(256, 2) void bucket_mfma_csr(
    const float* __restrict__ x, const int* __restrict__ ei,
    const float* __restrict__ pseudo, const float* __restrict__ weight,
    const int* __restrict__ list, const int* __restrict__ bstart,
    const int* __restrict__ hist, const int* __restrict__ rowstart,
    int* __restrict__ rcur, unsigned short* __restrict__ msg)
{
    __shared__ short XS[4][16 * KPAD];

    const int lane = threadIdx.x & 63;
    const int wid  = threadIdx.x >> 6;
    const int beta = blockIdx.x & (NBUCKET - 1);
    const int wGlob   = (blockIdx.x >> 4) * 4 + wid;
    const int wStride = (gridDim.x >> 4) * 4;

    const int lo0 = beta & 3, lo1 = beta >> 2;
    const int base = lo0 + 5 * lo1;
    const int offs[4] = {0, 1, 5, 6};
    const int q = lane >> 4;
    const int c = lane & 15;

    // B-fragments: Wstack[k=s*32+q*8+j][o=nt*16+c]
    s8v bfr[4][4];
#pragma unroll
    for (int s = 0; s < 4; ++s) {
        const float* wp = weight + (size_t)(base + offs[s]) * (CIN * COUT);
#pragma unroll
        for (int nt = 0; nt < 4; ++nt) {
            union { unsigned short u[8]; s8v v; } tmp;
#pragma unroll
            for (int j = 0; j < 8; ++j)
                tmp.u[j] = f2bf(wp[(q * 8 + j) * COUT + nt * 16 + c]);
            bfr[s][nt] = tmp.v;
        }
    }

    const int start  = bstart[beta];
    const int cnt    = hist[beta];
    const int ntiles = (cnt + 15) >> 4;

    for (int t = wGlob; t < ntiles; t += wStride) {
        const int ebase = start + t * 16;

        int rowv = 0, colv = 0, slotv = 0;
        float b0 = 0.f, b1 = 0.f, b2 = 0.f, b3 = 0.f;
        if (lane < 16 && (t * 16 + lane) < cnt) {
            const int e = list[ebase + lane];
            rowv = min(max(ei[e], 0), N_NODES - 1);
            colv = min(max(ei[E_EDGES + e], 0), N_NODES - 1);
            const float v0 = pseudo[2 * e]     * 4.0f;
            const float v1 = pseudo[2 * e + 1] * 4.0f;
            const float f0 = v0 - floorf(v0);
            const float f1 = v1 - floorf(v1);
            b0 = (1.0f - f0) * (1.0f - f1);
            b1 = f0 * (1.0f - f1);
            b2 = (1.0f - f0) * f1;
            b3 = f0 * f1;
            slotv = rowstart[rowv] + atomicAdd(&rcur[rowv], 1);  // row-CSR slot
        }

        // gather + scale + stage X' (16 x 128 bf16)
        {
            const int eg = lane >> 2, part = lane & 3;
            const int  gc = __shfl(colv, eg);
            const float ss0 = __shfl(b0, eg), ss1 = __shfl(b1, eg);
            const float ss2 = __shfl(b2, eg), ss3 = __shfl(b3, eg);
            const float ss[4] = {ss0, ss1, ss2, ss3};
            const float* xp = x + (size_t)gc * CIN + part * 8;
            float xv[8];
            *(f4v*)&xv[0] = *(const f4v*)xp;
            *(f4v*)&xv[4] = *(const f4v*)(xp + 4);
            short* dst = &XS[wid][eg * KPAD + part * 8];
#pragma unroll
            for (int s = 0; s < 4; ++s) {
                union { unsigned short u[8]; s8v v; } tmp;
#pragma unroll
                for (int j = 0; j < 8; ++j)
                    tmp.u[j] = f2bf(ss[s] * xv[j]);
                *(s8v*)(dst + s * 32) = tmp.v;
            }
        }
        __builtin_amdgcn_wave_barrier();

        s8v afr[4];
        {
            const short* ap = &XS[wid][c * KPAD + q * 8];
#pragma unroll
            for (int ks = 0; ks < 4; ++ks)
                afr[ks] = *(const s8v*)(ap + ks * 32);
        }
        __builtin_amdgcn_wave_barrier();

        f4v acc[4];
#pragma unroll
        for (int nt = 0; nt < 4; ++nt) {
            acc[nt] = (f4v){0.f, 0.f, 0.f, 0.f};
#pragma unroll
            for (int ks = 0; ks < 4; ++ks)
                acc[nt] = __builtin_amdgcn_mfma_f32_16x16x32_bf16(
                    afr[ks], bfr[ks][nt], acc[nt], 0, 0, 0);
        }

        // epilogue: acc -> bf16 in LDS [m][64], then coalesced 128B store per edge
#pragma unroll
        for (int r = 0; r < 4; ++r) {
            const int m = q * 4 + r;
#pragma unroll
            for (int nt = 0; nt < 4; ++nt)
                XS[wid][m * 64 + nt * 16 + c] = (short)f2bf(acc[nt][r]);
        }
        __builtin_amdgcn_wave_barrier();
        {
            const int m2 = lane >> 2;
            const int slot2 = __shfl(slotv, m2);
            const bool valid2 = (t * 16 + m2) < cnt;
            const short* sp = &XS[wid][lane * 16];
            s8v vlo = *(const s8v*)sp;
            s8v vhi = *(const s8v*)(sp + 8);
            if (valid2) {
                unsigned short* dst = msg + (size_t)slot2 * COUT + (lane & 3) * 16;
                *(s8v*)dst = vlo;
                *(s8v*)(dst + 8) = vhi;
            }
        }
        __builtin_amdgcn_wave_barrier();
    }
}

// pass E: per-node segment sum + root/bias fuse, single write per node
__global__ __launch_bounds__(256) void gather_final(
    const unsigned short* __restrict__ msg, const int* __restrict__ rowstart,
    const float* __restrict__ x, const float* __restrict__ root,
    const float* __restrict__ bias, float* __restrict__ out)
{
    const int wave   = (blockIdx.x * blockDim.x + threadIdx.x) >> 6;
    const int lane   = threadIdx.x & 63;
    const int nwaves = (gridDim.x * blockDim.x) >> 6;

    for (int n = wave; n < N_NODES; n += nwaves) {
        const int s  = rowstart[n];
        const int e2 = rowstart[n + 1];
        float acc = 0.f;
#pragma unroll 4
        for (int p = s; p < e2; ++p)
            acc += bf2f(msg[(size_t)p * COUT + lane]);
        float dg = (float)(e2 - s);
        dg = dg > 1.f ? dg : 1.f;
        const float* xp = x + (size_t)n * CIN;
        float rt = bias[lane];
#pragma unroll
        for (int i = 0; i < CIN; ++i)
            rt += xp[i] * root[i * COUT + lane];
        out[(size_t)n * COUT + lane] = acc / dg + rt;
    }
}

// ================= fallback (R4 atomic) path =================

__global__ __launch_bounds__(256) void count_fb(
    const int* __restrict__ ei, const float* __restrict__ pseudo,
    int* __restrict__ hist, float* __restrict__ deg)
{
    __shared__ int lh[NBUCKET];
    if (threadIdx.x < NBUCKET) lh[threadIdx.x] = 0;
    __syncthreads();
    const int e = blockIdx.x * 256 + threadIdx.x;
    if (e < E_EDGES) {
        int row = min(max(ei[e], 0), N_NODES - 1);
        const float v0 = pseudo[2 * e] * 4.0f, v1 = pseudo[2 * e + 1] * 4.0f;
        const int lo0 = min(max((int)floorf(v0), 0), 3);
        const int lo1 = min(max((int)floorf(v1), 0), 3);
        atomicAdd(&lh[lo0 + 4 * lo1], 1);
        atomicAdd(&deg[row], 1.0f);
    }
    __syncthreads();
    if (threadIdx.x < NBUCKET) atomicAdd(&hist[threadIdx.x], lh[threadIdx.x]);
}

__global__ void scan16_fb(const int* __restrict__ hist,
                          int* __restrict__ bstart, int* __restrict__ cursor)
{
    if (threadIdx.x == 0 && blockIdx.x == 0) {
        int acc = 0;
        for (int c = 0; c < NBUCKET; ++c) { bstart[c] = acc; cursor[c] = acc; acc += hist[c]; }
    }
}

__global__ __launch_bounds__(256, 2) void bucket_mfma_fb(
    const float* __restrict__ x, const int* __restrict__ ei,
    const float* __restrict__ pseudo, const float* __restrict__ weight,
    const int* __restrict__ list, const int* __restrict__ bstart,
    const int* __restrict__ hist, float* __restrict__ out)
{
    __shared__ short XS[4][16 * KPAD];
    const int lane = threadIdx.x & 63;
    const int wid  = threadIdx.x >> 6;
    const int beta = blockIdx.x & (NBUCKET - 1);
    const int wGlob   = (blockIdx.x >> 4) * 4 + wid;
    const int wStride = (gridDim.x >> 4) * 4;
    const int lo0 = beta & 3, lo1 = beta >> 2;
    const int base = lo0 + 5 * lo1;
    const int offs[4] = {0, 1, 5, 6};
    const int q = lane >> 4, c = lane & 15;

    s8v bfr[4][4];
#pragma unroll
    for (int s = 0; s < 4; ++s) {
        const float* wp = weight + (size_t)(base + offs[s]) * (CIN * COUT);
#pragma unroll
        for (int nt = 0; nt < 4; ++nt) {
            union { unsigned short u[8]; s8v v; } tmp;
#pragma unroll
            for (int j = 0; j < 8; ++j)
                tmp.u[j] = f2bf(wp[(q * 8 + j) * COUT + nt * 16 + c]);
            bfr[s][nt] = tmp.v;
        }
    }
    const int start = bstart[beta], cnt = hist[beta];
    const int ntiles = (cnt + 15) >> 4;

    for (int t = wGlob; t < ntiles; t += wStride) {
        const int ebase = start + t * 16;
        int rowv = 0, colv = 0;
        float b0 = 0.f, b1 = 0.f, b2 = 0.f, b3 = 0.f;
        if (lane < 16 && (t * 16 + lane) < cnt) {
            const int e = list[ebase + lane];
            rowv = min(max(ei[e], 0), N_NODES - 1);
            colv = min(max(ei[E_EDGES + e], 0), N_NODES - 1);
            const float v0 = pseudo[2 * e] * 4.0f, v1 = pseudo[2 * e + 1] * 4.0f;
            const float f0 = v0 - floorf(v0), f1 = v1 - floorf(v1);
            b0 = (1.0f - f0) * (1.0f - f1);
            b1 = f0 * (1.0f - f1);
            b2 = (1.0f - f0) * f1;
            b3 = f0 * f1;
        }
        {
            const int eg = lane >> 2, part = lane & 3;
            const int  gc = __shfl(colv, eg);
            const float ss0 = __shfl(b0, eg), ss1 = __shfl(b1, eg);
            const float ss2 = __shfl(b2, eg), ss3 = __shfl(b3, eg);
            const float ss[4] = {ss0, ss1, ss2, ss3};
            const float* xp = x + (size_t)gc * CIN + part * 8;
            float xv[8];
            *(f4v*)&xv[0] = *(const f4v*)xp;
            *(f4v*)&xv[4] = *(const f4v*)(xp + 4);
            short* dst = &XS[wid][eg * KPAD + part * 8];
#pragma unroll
            for (int s = 0; s < 4; ++s) {
                union { unsigned short u[8]; s8v v; } tmp;
#pragma unroll
                for (int j = 0; j < 8; ++j)
                    tmp.u[j] = f2bf(ss[s] * xv[j]);
                *(s8v*)(dst + s * 32) = tmp.v;
            }
        }
        __builtin_amdgcn_wave_barrier();
        s8v afr[4];
        {
            const short* ap = &XS[wid][c * KPAD + q * 8];
#pragma unroll
            for (int ks = 0; ks < 4; ++ks)
                afr[ks] = *(const s8v*)(ap + ks * 32);
        }
        __builtin_amdgcn_wave_barrier();
        f4v acc[4];
#pragma unroll
        for (int nt = 0; nt < 4; ++nt) {
            acc[nt] = (f4v){0.f, 0.f, 0.f, 0.f};
#pragma unroll
            for (int ks = 0; ks < 4; ++ks)
                acc[nt] = __builtin_amdgcn_mfma_f32_16x16x32_bf16(
                    afr[ks], bfr[ks][nt], acc[nt], 0, 0, 0);
        }
#pragma unroll
        for (int r = 0; r < 4; ++r) {
            const int m = q * 4 + r;
            const int orow = __shfl(rowv, m);
#pragma unroll
            for (int nt = 0; nt < 4; ++nt)
                atomicAdd(&out[(size_t)orow * COUT + nt * 16 + c], acc[nt][r]);
        }
    }
}

__global__ __launch_bounds__(256) void final_fb(
    const float* __restrict__ x, const float* __restrict__ root,
    const float* __restrict__ bias, const float* __restrict__ deg,
    float* __restrict__ out)
{
    const int wave   = (blockIdx.x * blockDim.x + threadIdx.x) >> 6;
    const int lane   = threadIdx.x & 63;
    const int nwaves = (gridDim.x * blockDim.x) >> 6;
    for (int n = wave; n < N_NODES; n += nwaves) {
        const float* xp = x + (size_t)n * CIN;
        float acc = bias[lane];
#pragma unroll
        for (int i = 0; i < CIN; ++i)
            acc += xp[i] * root[i * COUT + lane];
        float dg = deg[n];
        dg = dg > 1.0f ? dg : 1.0f;
        const size_t idx = (size_t)n * COUT + lane;
        out[idx] = out[idx] / dg + acc;
    }
}

extern "C" void kernel_launch(void* const* d_in, const int* in_sizes, int n_in,
                              void* d_out, int out_size, void* d_ws, size_t ws_size,
                              hipStream_t stream) {
    const float* x      = (const float*)d_in[0];
    const int*   ei     = (const int*)d_in[1];
    const float* pseudo = (const float*)d_in[2];
    const float* weight = (const float*)d_in[3];
    const float* root   = (const float*)d_in[4];
    const float* bias   = (const float*)d_in[5];
    float* out = (float*)d_out;

    // main-path ws layout (int elements)
    int* wsI = (int*)d_ws;
    int* hist     = wsI;                       // 16
    int* bstartA  = wsI + 16;                  // 16
    int* cursorA  = wsI + 32;                  // 16 (+16 pad)
    int* degi     = wsI + 64;                  // 50000
    int* rcur     = wsI + 64 + N_NODES;        // 50000
    int* rowstart = wsI + 64 + 2 * N_NODES;    // 50001 (+pad)
    int* list     = wsI + 64 + 3 * N_NODES + 16;                 // 800000
    unsigned short* msg = (unsigned short*)(wsI + 64 + 3 * N_NODES + 16 + E_EDGES);
    const size_t needed = (size_t)(64 + 3 * N_NODES + 16 + E_EDGES) * 4
                        + (size_t)E_EDGES * COUT * 2;  // ~106.2 MB

    const int eblocks = (E_EDGES + 255) / 256;

    if (ws_size >= needed) {
        // zero hist(+pads) + degi + rcur in one shot
        hipMemsetAsync(d_ws, 0, (size_t)(64 + 2 * N_NODES) * 4, stream);
        count_csr      <<<eblocks, 256, 0, stream>>>(ei, pseudo, hist, degi);
        scan_all       <<<1, 1024, 0, stream>>>(hist, bstartA, cursorA, degi, rowstart);
        scatter_kernel <<<eblocks, 256, 0, stream>>>(pseudo, cursorA, list);
        bucket_mfma_csr<<<16 * 128, 256, 0, stream>>>(x, ei, pseudo, weight, list,
                                                      bstartA, hist, rowstart, rcur, msg);
        gather_final   <<<1024, 256, 0, stream>>>(msg, rowstart, x, root, bias, out);
    } else {
        // R4 fallback layout
        char* w = (char*)d_ws;
        float* degF   = (float*)w;
        int*   histF  = (int*)(w + 200064);
        int*   bstF   = (int*)(w + 200128);
        int*   curF   = (int*)(w + 200192);
        int*   listF  = (int*)(w + 200256);

        hipMemsetAsync(out, 0, sizeof(float) * (size_t)N_NODES * COUT, stream);
        hipMemsetAsync(degF, 0, sizeof(float) * (size_t)N_NODES, stream);
        hipMemsetAsync(histF, 0, 192, stream);

        count_fb      <<<eblocks, 256, 0, stream>>>(ei, pseudo, histF, degF);
        scan16_fb     <<<1, 64, 0, stream>>>(histF, bstF, curF);
        scatter_kernel<<<eblocks, 256, 0, stream>>>(pseudo, curF, listF);
        bucket_mfma_fb<<<16 * 64, 256, 0, stream>>>(x, ei, pseudo, weight, listF,
                                                    bstF, histF, out);
        final_fb      <<<1024, 256, 0, stream>>>(x, root, bias, degF, out);
    }
}

// Round 6
// 270.623 us; speedup vs baseline: 4.2468x; 1.1533x over previous
//
#include <hip/hip_runtime.h>

#define N_NODES 50000
#define E_EDGES 800000
#define CIN     32
#define COUT    64
#define NBUCKET 16   // (lo0, lo1) in [0,3]^2
#define KPAD    136  // 128 bf16 + 8 pad
#define SCANB   1024
#define NSCANBLK ((N_NODES + SCANB - 1) / SCANB)   // 49

typedef __attribute__((ext_vector_type(8))) short s8v;   // 8 bf16 = 4 VGPRs
typedef __attribute__((ext_vector_type(4))) float f4v;
typedef __attribute__((ext_vector_type(4))) unsigned short u4v;

static __device__ inline unsigned short f2bf(float f) {  // RTNE fp32->bf16
    unsigned u = __builtin_bit_cast(unsigned, f);
    u += 0x7fff + ((u >> 16) & 1);
    return (unsigned short)(u >> 16);
}
static __device__ inline float bf2f(unsigned short h) {
    unsigned u = ((unsigned)h) << 16;
    return __builtin_bit_cast(float, u);
}

// ================= main (CSR) path =================

// x (fp32) -> xbf (bf16), 4 elems/thread
__global__ __launch_bounds__(256) void x2bf_kernel(
    const float* __restrict__ x, unsigned short* __restrict__ xbf)
{
    const int i = blockIdx.x * 256 + threadIdx.x;
    const int total = N_NODES * CIN / 4;
    if (i < total) {
        f4v v = *(const f4v*)(x + (size_t)i * 4);
        u4v o = { f2bf(v[0]), f2bf(v[1]), f2bf(v[2]), f2bf(v[3]) };
        *(u4v*)(xbf + (size_t)i * 4) = o;
    }
}

// pass A: cell histogram + integer degree count
__global__ __launch_bounds__(256) void count_csr(
    const int* __restrict__ ei, const float* __restrict__ pseudo,
    int* __restrict__ hist, int* __restrict__ degi)
{
    __shared__ int lh[NBUCKET];
    if (threadIdx.x < NBUCKET) lh[threadIdx.x] = 0;
    __syncthreads();
    const int e = blockIdx.x * 256 + threadIdx.x;
    if (e < E_EDGES) {
        int row = min(max(ei[e], 0), N_NODES - 1);
        const float v0 = pseudo[2 * e] * 4.0f, v1 = pseudo[2 * e + 1] * 4.0f;
        const int lo0 = min(max((int)floorf(v0), 0), 3);
        const int lo1 = min(max((int)floorf(v1), 0), 3);
        atomicAdd(&lh[lo0 + 4 * lo1], 1);
        atomicAdd(&degi[row], 1);
    }
    __syncthreads();
    if (threadIdx.x < NBUCKET) atomicAdd(&hist[threadIdx.x], lh[threadIdx.x]);
}

// pass B1: per-block local exclusive scan of degi, block sums out
__global__ __launch_bounds__(1024) void scan_blocks(
    const int* __restrict__ degi, int* __restrict__ rowstart, int* __restrict__ bsum)
{
    __shared__ int wsum[16];
    __shared__ int woff[16];
    const int tid = threadIdx.x, lane = tid & 63, wid = tid >> 6;
    const int n = blockIdx.x * SCANB + tid;
    const int v = (n < N_NODES) ? degi[n] : 0;
    int val = v;
#pragma unroll
    for (int off = 1; off < 64; off <<= 1) {
        int t = __shfl_up(val, off);
        if (lane >= off) val += t;
    }
    if (lane == 63) wsum[wid] = val;
    __syncthreads();
    if (tid == 0) {
        int a = 0;
#pragma unroll
        for (int w = 0; w < 16; ++w) { woff[w] = a; a += wsum[w]; }
        bsum[blockIdx.x] = a;
    }
    __syncthreads();
    if (n < N_NODES) rowstart[n] = woff[wid] + (val - v);
}

// pass B2: scan 49 block sums + 16-bucket scan (tiny)
__global__ void scan_tops(const int* __restrict__ hist, int* __restrict__ bstart,
                          int* __restrict__ cursor, const int* __restrict__ bsum,
                          int* __restrict__ boffs, int* __restrict__ rowstart)
{
    if (threadIdx.x == 0 && blockIdx.x == 0) {
        int acc = 0;
        for (int c = 0; c < NBUCKET; ++c) { bstart[c] = acc; cursor[c] = acc; acc += hist[c]; }
        int a = 0;
        for (int b = 0; b < NSCANBLK; ++b) { boffs[b] = a; a += bsum[b]; }
        rowstart[N_NODES] = a;
    }
}

// pass B3: add block offsets
__global__ __launch_bounds__(1024) void scan_add(
    int* __restrict__ rowstart, const int* __restrict__ boffs)
{
    const int n = blockIdx.x * SCANB + threadIdx.x;
    if (n < N_NODES && blockIdx.x > 0) rowstart[n] += boffs[blockIdx.x];
}

// pass C: scatter edge ids into cell-bucket lists
__global__ __launch_bounds__(256) void scatter_kernel(
    const float* __restrict__ pseudo, int* __restrict__ cursor, int* __restrict__ list)
{
    __shared__ int lh[NBUCKET];
    __shared__ int lbase[NBUCKET];
    if (threadIdx.x < NBUCKET) lh[threadIdx.x] = 0;
    __syncthreads();
    const int e = blockIdx.x * 256 + threadIdx.x;
    int cell = 0, myoff = 0;
    if (e < E_EDGES) {
        const float v0 = pseudo[2 * e] * 4.0f, v1 = pseudo[2 * e + 1] * 4.0f;
        const int lo0 = min(max((int)floorf(v0), 0), 3);
        const int lo1 = min(max((int)floorf(v1), 0), 3);
        cell = lo0 + 4 * lo1;
        myoff = atomicAdd(&lh[cell], 1);
    }
    __syncthreads();
    if (threadIdx.x < NBUCKET)
        lbase[threadIdx.x] = atomicAdd(&cursor[threadIdx.x], lh[threadIdx.x]);
    __syncthreads();
    if (e < E_EDGES)
        list[lbase[cell] + myoff] = e;
}

// pass D: per-bucket MFMA; write per-edge bf16 msg to row-sorted slot
template<bool XBF>
__global__ __launch_bounds__(256, 2) void bucket_mfma_csr(
    const float* __restrict__ x, const unsigned short* __restrict__ xbf,
    const int* __restrict__ ei, const float* __restrict__ pseudo,
    const float* __restrict__ weight, const int* __restrict__ list,
    const int* __restrict__ bstart, const int* __restrict__ hist,
    const int* __restrict__ rowstart, int* __restrict__ rcur,
    unsigned short* __restrict__ msg)
{
    __shared__ short XS[4][16 * KPAD];

    const int lane = threadIdx.x & 63;
    const int wid  = threadIdx.x >> 6;
    const int beta = blockIdx.x & (NBUCKET - 1);
    const int wGlob   = (blockIdx.x >> 4) * 4 + wid;
    const int wStride = (gridDim.x >> 4) * 4;

    const int lo0 = beta & 3, lo1 = beta >> 2;
    const int base = lo0 + 5 * lo1;
    const int offs[4] = {0, 1, 5, 6};
    const int q = lane >> 4;
    const int c = lane & 15;

    // B-fragments: Wstack[k=s*32+q*8+j][o=nt*16+c]
    s8v bfr[4][4];
#pragma unroll
    for (int s = 0; s < 4; ++s) {
        const float* wp = weight + (size_t)(base + offs[s]) * (CIN * COUT);
#pragma unroll
        for (int nt = 0; nt < 4; ++nt) {
            union { unsigned short u[8]; s8v v; } tmp;
#pragma unroll
            for (int j = 0; j < 8; ++j)
                tmp.u[j] = f2bf(wp[(q * 8 + j) * COUT + nt * 16 + c]);
            bfr[s][nt] = tmp.v;
        }
    }

    const int start  = bstart[beta];
    const int cnt    = hist[beta];
    const int ntiles = (cnt + 15) >> 4;

    for (int t = wGlob; t < ntiles; t += wStride) {
        const int ebase = start + t * 16;

        int rowv = 0, colv = 0, slotv = 0;
        float b0 = 0.f, b1 = 0.f, b2 = 0.f, b3 = 0.f;
        if (lane < 16 && (t * 16 + lane) < cnt) {
            const int e = list[ebase + lane];
            rowv = min(max(ei[e], 0), N_NODES - 1);
            colv = min(max(ei[E_EDGES + e], 0), N_NODES - 1);
            const float v0 = pseudo[2 * e]     * 4.0f;
            const float v1 = pseudo[2 * e + 1] * 4.0f;
            const float f0 = v0 - floorf(v0);
            const float f1 = v1 - floorf(v1);
            b0 = (1.0f - f0) * (1.0f - f1);
            b1 = f0 * (1.0f - f1);
            b2 = (1.0f - f0) * f1;
            b3 = f0 * f1;
            slotv = rowstart[rowv] + atomicAdd(&rcur[rowv], 1);
        }

        // gather + scale + stage X' (16 x 128 bf16)
        {
            const int eg = lane >> 2, part = lane & 3;
            const int  gc = __shfl(colv, eg);
            const float ss0 = __shfl(b0, eg), ss1 = __shfl(b1, eg);
            const float ss2 = __shfl(b2, eg), ss3 = __shfl(b3, eg);
            const float ss[4] = {ss0, ss1, ss2, ss3};
            float xv[8];
            if constexpr (XBF) {
                union { unsigned short u[8]; s8v v; } xin;
                xin.v = *(const s8v*)(xbf + (size_t)gc * CIN + part * 8);
#pragma unroll
                for (int j = 0; j < 8; ++j) xv[j] = bf2f(xin.u[j]);
            } else {
                const float* xp = x + (size_t)gc * CIN + part * 8;
                *(f4v*)&xv[0] = *(const f4v*)xp;
                *(f4v*)&xv[4] = *(const f4v*)(xp + 4);
            }
            short* dst = &XS[wid][eg * KPAD + part * 8];
#pragma unroll
            for (int s = 0; s < 4; ++s) {
                union { unsigned short u[8]; s8v v; } tmp;
#pragma unroll
                for (int j = 0; j < 8; ++j)
                    tmp.u[j] = f2bf(ss[s] * xv[j]);
                *(s8v*)(dst + s * 32) = tmp.v;
            }
        }
        __builtin_amdgcn_wave_barrier();

        s8v afr[4];
        {
            const short* ap = &XS[wid][c * KPAD + q * 8];
#pragma unroll
            for (int ks = 0; ks < 4; ++ks)
                afr[ks] = *(const s8v*)(ap + ks * 32);
        }
        __builtin_amdgcn_wave_barrier();

        f4v acc[4];
#pragma unroll
        for (int nt = 0; nt < 4; ++nt) {
            acc[nt] = (f4v){0.f, 0.f, 0.f, 0.f};
#pragma unroll
            for (int ks = 0; ks < 4; ++ks)
                acc[nt] = __builtin_amdgcn_mfma_f32_16x16x32_bf16(
                    afr[ks], bfr[ks][nt], acc[nt], 0, 0, 0);
        }

        // epilogue: acc -> bf16 tile in LDS, coalesced 128B store per edge
#pragma unroll
        for (int r = 0; r < 4; ++r) {
            const int m = q * 4 + r;
#pragma unroll
            for (int nt = 0; nt < 4; ++nt)
                XS[wid][m * 64 + nt * 16 + c] = (short)f2bf(acc[nt][r]);
        }
        __builtin_amdgcn_wave_barrier();
        {
            const int m2 = lane >> 2;
            const int slot2 = __shfl(slotv, m2);
            const bool valid2 = (t * 16 + m2) < cnt;
            const short* sp = &XS[wid][lane * 16];
            s8v vlo = *(const s8v*)sp;
            s8v vhi = *(const s8v*)(sp + 8);
            if (valid2) {
                unsigned short* dst = msg + (size_t)slot2 * COUT + (lane & 3) * 16;
                *(s8v*)dst = vlo;
                *(s8v*)(dst + 8) = vhi;
            }
        }
        __builtin_amdgcn_wave_barrier();
    }
}

// pass E: per-node segment sum + root/bias fuse
__global__ __launch_bounds__(256) void gather_final(
    const unsigned short* __restrict__ msg, const int* __restrict__ rowstart,
    const float* __restrict__ x, const float* __restrict__ root,
    const float* __restrict__ bias, float* __restrict__ out)
{
    const int wave   = (blockIdx.x * blockDim.x + threadIdx.x) >> 6;
    const int lane   = threadIdx.x & 63;
    const int nwaves = (gridDim.x * blockDim.x) >> 6;

    for (int n = wave; n < N_NODES; n += nwaves) {
        const int s  = rowstart[n];
        const int e2 = rowstart[n + 1];
        float acc = 0.f;
#pragma unroll 4
        for (int p = s; p < e2; ++p)
            acc += bf2f(msg[(size_t)p * COUT + lane]);
        float dg = (float)(e2 - s);
        dg = dg > 1.f ? dg : 1.f;
        const float* xp = x + (size_t)n * CIN;
        float rt = bias[lane];
#pragma unroll
        for (int i = 0; i < CIN; ++i)
            rt += xp[i] * root[i * COUT + lane];
        out[(size_t)n * COUT + lane] = acc / dg + rt;
    }
}

// ================= fallback (R4 atomic) path =================

__global__ __launch_bounds__(256) void count_fb(
    const int* __restrict__ ei, const float* __restrict__ pseudo,
    int* __restrict__ hist, float* __restrict__ deg)
{
    __shared__ int lh[NBUCKET];
    if (threadIdx.x < NBUCKET) lh[threadIdx.x] = 0;
    __syncthreads();
    const int e = blockIdx.x * 256 + threadIdx.x;
    if (e < E_EDGES) {
        int row = min(max(ei[e], 0), N_NODES - 1);
        const float v0 = pseudo[2 * e] * 4.0f, v1 = pseudo[2 * e + 1] * 4.0f;
        const int lo0 = min(max((int)floorf(v0), 0), 3);
        const int lo1 = min(max((int)floorf(v1), 0), 3);
        atomicAdd(&lh[lo0 + 4 * lo1], 1);
        atomicAdd(&deg[row], 1.0f);
    }
    __syncthreads();
    if (threadIdx.x < NBUCKET) atomicAdd(&hist[threadIdx.x], lh[threadIdx.x]);
}

__global__ void scan16_fb(const int* __restrict__ hist,
                          int* __restrict__ bstart, int* __restrict__ cursor)
{
    if (threadIdx.x == 0 && blockIdx.x == 0) {
        int acc = 0;
        for (int c = 0; c < NBUCKET; ++c) { bstart[c] = acc; cursor[c] = acc; acc += hist[c]; }
    }
}

__global__ __launch_bounds__(256, 2) void bucket_mfma_fb(
    const float* __restrict__ x, const int* __restrict__ ei,
    const float* __restrict__ pseudo, const float* __restrict__ weight,
    const int* __restrict__ list, const int* __restrict__ bstart,
    const int* __restrict__ hist, float* __restrict__ out)
{
    __shared__ short XS[4][16 * KPAD];
    const int lane = threadIdx.x & 63;
    const int wid  = threadIdx.x >> 6;
    const int beta = blockIdx.x & (NBUCKET - 1);
    const int wGlob   = (blockIdx.x >> 4) * 4 + wid;
    const int wStride = (gridDim.x >> 4) * 4;
    const int lo0 = beta & 3, lo1 = beta >> 2;
    const int base = lo0 + 5 * lo1;
    const int offs[4] = {0, 1, 5, 6};
    const int q = lane >> 4, c = lane & 15;

    s8v bfr[4][4];
#pragma unroll
    for (int s = 0; s < 4; ++s) {
        const float* wp = weight + (size_t)(base + offs[s]) * (CIN * COUT);
#pragma unroll
        for (int nt = 0; nt < 4; ++nt) {
            union { unsigned short u[8]; s8v v; } tmp;
#pragma unroll
            for (int j = 0; j < 8; ++j)
                tmp.u[j] = f2bf(wp[(q * 8 + j) * COUT + nt * 16 + c]);
            bfr[s][nt] = tmp.v;
        }
    }
    const int start = bstart[beta], cnt = hist[beta];
    const int ntiles = (cnt + 15) >> 4;

    for (int t = wGlob; t < ntiles; t += wStride) {
        const int ebase = start + t * 16;
        int rowv = 0, colv = 0;
        float b0 = 0.f, b1 = 0.f, b2 = 0.f, b3 = 0.f;
        if (lane < 16 && (t * 16 + lane) < cnt) {
            const int e = list[ebase + lane];
            rowv = min(max(ei[e], 0), N_NODES - 1);
            colv = min(max(ei[E_EDGES + e], 0), N_NODES - 1);
            const float v0 = pseudo[2 * e] * 4.0f, v1 = pseudo[2 * e + 1] * 4.0f;
            const float f0 = v0 - floorf(v0), f1 = v1 - floorf(v1);
            b0 = (1.0f - f0) * (1.0f - f1);
            b1 = f0 * (1.0f - f1);
            b2 = (1.0f - f0) * f1;
            b3 = f0 * f1;
        }
        {
            const int eg = lane >> 2, part = lane & 3;
            const int  gc = __shfl(colv, eg);
            const float ss0 = __shfl(b0, eg), ss1 = __shfl(b1, eg);
            const float ss2 = __shfl(b2, eg), ss3 = __shfl(b3, eg);
            const float ss[4] = {ss0, ss1, ss2, ss3};
            const float* xp = x + (size_t)gc * CIN + part * 8;
            float xv[8];
            *(f4v*)&xv[0] = *(const f4v*)xp;
            *(f4v*)&xv[4] = *(const f4v*)(xp + 4);
            short* dst = &XS[wid][eg * KPAD + part * 8];
#pragma unroll
            for (int s = 0; s < 4; ++s) {
                union { unsigned short u[8]; s8v v; } tmp;
#pragma unroll
                for (int j = 0; j < 8; ++j)
                    tmp.u[j] = f2bf(ss[s] * xv[j]);
                *(s8v*)(dst + s * 32) = tmp.v;
            }
        }
        __builtin_amdgcn_wave_barrier();
        s8v afr[4];
        {
            const short* ap = &XS[wid][c * KPAD + q * 8];
#pragma unroll
            for (int ks = 0; ks < 4; ++ks)
                afr[ks] = *(const s8v*)(ap + ks * 32);
        }
        __builtin_amdgcn_wave_barrier();
        f4v acc[4];
#pragma unroll
        for (int nt = 0; nt < 4; ++nt) {
            acc[nt] = (f4v){0.f, 0.f, 0.f, 0.f};
#pragma unroll
            for (int ks = 0; ks < 4; ++ks)
                acc[nt] = __builtin_amdgcn_mfma_f32_16x16x32_bf16(
                    afr[ks], bfr[ks][nt], acc[nt], 0, 0, 0);
        }
#pragma unroll
        for (int r = 0; r < 4; ++r) {
            const int m = q * 4 + r;
            const int orow = __shfl(rowv, m);
#pragma unroll
            for (int nt = 0; nt < 4; ++nt)
                atomicAdd(&out[(size_t)orow * COUT + nt * 16 + c], acc[nt][r]);
        }
    }
}

__global__ __launch_bounds__(256) void final_fb(
    const float* __restrict__ x, const float* __restrict__ root,
    const float* __restrict__ bias, const float* __restrict__ deg,
    float* __restrict__ out)
{
    const int wave   = (blockIdx.x * blockDim.x + threadIdx.x) >> 6;
    const int lane   = threadIdx.x & 63;
    const int nwaves = (gridDim.x * blockDim.x) >> 6;
    for (int n = wave; n < N_NODES; n += nwaves) {
        const float* xp = x + (size_t)n * CIN;
        float acc = bias[lane];
#pragma unroll
        for (int i = 0; i < CIN; ++i)
            acc += xp[i] * root[i * COUT + lane];
        float dg = deg[n];
        dg = dg > 1.0f ? dg : 1.0f;
        const size_t idx = (size_t)n * COUT + lane;
        out[idx] = out[idx] / dg + acc;
    }
}

extern "C" void kernel_launch(void* const* d_in, const int* in_sizes, int n_in,
                              void* d_out, int out_size, void* d_ws, size_t ws_size,
                              hipStream_t stream) {
    const float* x      = (const float*)d_in[0];
    const int*   ei     = (const int*)d_in[1];
    const float* pseudo = (const float*)d_in[2];
    const float* weight = (const float*)d_in[3];
    const float* root   = (const float*)d_in[4];
    const float* bias   = (const float*)d_in[5];
    float* out = (float*)d_out;

    // ws layout (int elements)
    int* wsI = (int*)d_ws;
    int* hist     = wsI;                        // 16
    int* bstartA  = wsI + 16;                   // 16
    int* cursorA  = wsI + 32;                   // 16 (+16 pad)
    int* degi     = wsI + 64;                   // 50000
    int* rcur     = wsI + 50064;                // 50000
    int* rowstart = wsI + 100064;               // 50001 (+15 pad)
    int* bsum     = wsI + 150080;               // 64
    int* boffs    = wsI + 150144;               // 64
    int* list     = wsI + 150208;               // 800000
    unsigned short* xbf = (unsigned short*)(wsI + 950208);   // 1.6M bf16
    unsigned short* msgA = (unsigned short*)(wsI + 1750208); // with xbf
    unsigned short* msgB = (unsigned short*)(wsI + 950208);  // without xbf
    const size_t msg_bytes = (size_t)E_EDGES * COUT * 2;
    const size_t needed_A = (size_t)1750208 * 4 + msg_bytes; // ~104.3 MiB
    const size_t needed_B = (size_t)950208 * 4 + msg_bytes;  // ~101.3 MiB

    const int eblocks = (E_EDGES + 255) / 256;

    if (ws_size >= needed_B) {
        const bool useXbf = ws_size >= needed_A;
        unsigned short* msg = useXbf ? msgA : msgB;

        hipMemsetAsync(d_ws, 0, (size_t)100064 * 4, stream);  // hist..rcur
        if (useXbf)
            x2bf_kernel<<<(N_NODES * CIN / 4 + 255) / 256, 256, 0, stream>>>(x, xbf);
        count_csr  <<<eblocks, 256, 0, stream>>>(ei, pseudo, hist, degi);
        scan_blocks<<<NSCANBLK, 1024, 0, stream>>>(degi, rowstart, bsum);
        scan_tops  <<<1, 64, 0, stream>>>(hist, bstartA, cursorA, bsum, boffs, rowstart);
        scan_add   <<<NSCANBLK, 1024, 0, stream>>>(rowstart, boffs);
        scatter_kernel<<<eblocks, 256, 0, stream>>>(pseudo, cursorA, list);
        if (useXbf)
            bucket_mfma_csr<true><<<16 * 128, 256, 0, stream>>>(
                x, xbf, ei, pseudo, weight, list, bstartA, hist, rowstart, rcur, msg);
        else
            bucket_mfma_csr<false><<<16 * 128, 256, 0, stream>>>(
                x, xbf, ei, pseudo, weight, list, bstartA, hist, rowstart, rcur, msg);
        gather_final<<<1024, 256, 0, stream>>>(msg, rowstart, x, root, bias, out);
    } else {
        // R4 fallback layout
        char* w = (char*)d_ws;
        float* degF   = (float*)w;
        int*   histF  = (int*)(w + 200064);
        int*   bstF   = (int*)(w + 200128);
        int*   curF   = (int*)(w + 200192);
        int*   listF  = (int*)(w + 200256);

        hipMemsetAsync(out, 0, sizeof(float) * (size_t)N_NODES * COUT, stream);
        hipMemsetAsync(degF, 0, sizeof(float) * (size_t)N_NODES, stream);
        hipMemsetAsync(histF, 0, 192, stream);

        count_fb      <<<eblocks, 256, 0, stream>>>(ei, pseudo, histF, degF);
        scan16_fb     <<<1, 64, 0, stream>>>(histF, bstF, curF);
        scatter_kernel<<<eblocks, 256, 0, stream>>>(pseudo, curF, listF);
        bucket_mfma_fb<<<16 * 64, 256, 0, stream>>>(x, ei, pseudo, weight, listF,
                                                    bstF, histF, out);
        final_fb      <<<1024, 256, 0, stream>>>(x, root, bias, degF, out);
    }
}